// Round 16
// baseline (851.493 us; speedup 1.0000x reference)
//
#include <hip/hip_runtime.h>

typedef __attribute__((ext_vector_type(8))) short short8;
typedef __attribute__((ext_vector_type(4))) float f32x4;

__device__ __forceinline__ ushort f2bf(float x) {
  unsigned u = __builtin_bit_cast(unsigned, x);
  u = (u + 0x7fffu + ((u >> 16) & 1u)) >> 16;
  return (ushort)u;
}
__device__ __forceinline__ float bf2f(ushort x) {
  return __builtin_bit_cast(float, ((unsigned)x) << 16);
}

#define AS1CP(p) ((const __attribute__((address_space(1))) unsigned int*)(p))
#define AS3CP(p) ((__attribute__((address_space(3))) unsigned int*)(p))
#define GLDS(g, l, SZ) __builtin_amdgcn_global_load_lds(AS1CP(g), AS3CP(l), SZ, 0, 0)

// ---------------- input fp32 -> bf16 ----------------
__global__ __launch_bounds__(256) void k_cvt(const float* __restrict__ in,
                                             ushort* __restrict__ out, int n4) {
  int i = blockIdx.x * 256 + threadIdx.x;
  if (i >= n4) return;
  float4 v = reinterpret_cast<const float4*>(in)[i];
  ushort4 o;
  o.x = f2bf(v.x); o.y = f2bf(v.y); o.z = f2bf(v.z); o.w = f2bf(v.w);
  reinterpret_cast<ushort4*>(out)[i] = o;
}

// ------------- transpose fp32 [K][N] -> bf16 [N][K] (plain) -------------
__global__ __launch_bounds__(256) void k_transpose(const float* __restrict__ W,
                                                   ushort* __restrict__ Wt,
                                                   int N, int K) {
  __shared__ float tile[32][33];
  int bx = blockIdx.x * 32;
  int by = blockIdx.y * 32;
  int tx = threadIdx.x, ty = threadIdx.y;  // 32 x 8
#pragma unroll
  for (int i = 0; i < 32; i += 8)
    tile[ty + i][tx] = W[(size_t)(by + ty + i) * N + bx + tx];
  __syncthreads();
#pragma unroll
  for (int i = 0; i < 32; i += 8)
    Wt[(size_t)(bx + ty + i) * K + by + tx] = f2bf(tile[tx][ty + i]);
}

// ------ transpose + planar-pair permutation for SRU weights ------
template <int KKp>
__global__ __launch_bounds__(256) void k_transpose_sru(const float* __restrict__ W,
                                                       ushort* __restrict__ Wt,
                                                       int N, int K) {
  __shared__ float tile[32][33];
  int bx = blockIdx.x * 32;
  int by = blockIdx.y * 32;
  int tx = threadIdx.x, ty = threadIdx.y;
#pragma unroll
  for (int i = 0; i < 32; i += 8)
    tile[ty + i][tx] = W[(size_t)(by + ty + i) * N + bx + tx];
  __syncthreads();
#pragma unroll
  for (int i = 0; i < 32; i += 8) {
    int c = bx + ty + i;
    int ch = c / KKp, j = c - ch * KKp;
    int nc = (j < 2) ? (ch * 2 + j) : ((j == 2) ? (2048 + ch) : (3072 + ch));
    Wt[(size_t)nc * K + by + tx] = f2bf(tile[tx][ty + i]);
  }
}

// ------------- GEMM 256x256: C = A[M][K] * Bt[N][K], bf16 MFMA -------------
// BK=64 as two K=32 sub-planes; 512 threads = 8 waves (2M x 4N), per-wave
// output 128x64. LDS 128KB double-buffer: ls[buf][plane][256 rows x 32 elems]
// (64B rows, proven chunk swizzle). Per tile, 2 phases:
//  A: issue next-tile plane0 (4 GLDS), vmcnt(4) [counted, never drains],
//     barrier, 32 MFMA (setprio);  B: issue plane1, 32 MFMA, barrier.
// 64 MFMA per barrier-pair; full-tile prefetch distance.
template <int BF16OUT>
__global__ __launch_bounds__(512, 1) void k_gemm256(const ushort* __restrict__ A,
                                                    const ushort* __restrict__ Bt,
                                                    void* __restrict__ Cv,
                                                    int K, int N) {
  __shared__ __align__(16) ushort lsA[2][2][8192];
  __shared__ __align__(16) ushort lsB[2][2][8192];
  const int tid = threadIdx.x;
  const int bm = blockIdx.x, bn = blockIdx.y;
  const int w = tid >> 6, lane = tid & 63;
  const int wm = (w >> 2) * 128, wn = (w & 3) * 64;
  const int lr = lane & 15, lg = lane >> 4;
  const int rx = (lr >> 1) & 3;
  f32x4 acc[8][4] = {};
  // staging: lane covers row w*32 (+16 for half h) + (lane>>2), swizzled chunk
  const int swk = ((lane & 3) ^ ((lane >> 3) & 3)) * 8;
  const ushort* Asrc = A + (size_t)(bm * 256 + w * 32 + (lane >> 2)) * K + swk;
  const ushort* Bsrc = Bt + (size_t)(bn * 256 + w * 32 + (lane >> 2)) * K + swk;
  const int nt = K >> 6;

#define STAGE_HALF(BUF, KT, S)                                            \
  {                                                                       \
    GLDS(Asrc + (KT) + (S) * 32, &lsA[BUF][S][w * 1024], 16);             \
    GLDS(Asrc + (size_t)16 * K + (KT) + (S) * 32, &lsA[BUF][S][w * 1024 + 512], 16); \
    GLDS(Bsrc + (KT) + (S) * 32, &lsB[BUF][S][w * 1024], 16);             \
    GLDS(Bsrc + (size_t)16 * K + (KT) + (S) * 32, &lsB[BUF][S][w * 1024 + 512], 16); \
  }

  STAGE_HALF(0, 0, 0);
  STAGE_HALF(0, 0, 1);
  asm volatile("s_waitcnt vmcnt(0)" ::: "memory");
  asm volatile("s_barrier" ::: "memory");

  for (int t = 0; t < nt; ++t) {
    const int cur = t & 1;
    const int nb = cur ^ 1;
    // ---- phase A (sub-plane 0) ----
    if (t + 1 < nt) {
      STAGE_HALF(nb, (t + 1) * 64, 0);
      asm volatile("s_waitcnt vmcnt(4)" ::: "memory");  // tile t (8 ops) landed
    } else {
      asm volatile("s_waitcnt vmcnt(0)" ::: "memory");
    }
    asm volatile("s_barrier" ::: "memory");  // all waves' tile-t DMA landed
    {
      short8 af[8], bf[4];
#pragma unroll
      for (int i = 0; i < 8; ++i)
        af[i] = *(const short8*)&lsA[cur][0][(wm + i * 16 + lr) * 32 + (lg ^ rx) * 8];
#pragma unroll
      for (int j = 0; j < 4; ++j)
        bf[j] = *(const short8*)&lsB[cur][0][(wn + j * 16 + lr) * 32 + (lg ^ rx) * 8];
      __builtin_amdgcn_s_setprio(1);
#pragma unroll
      for (int i = 0; i < 8; ++i)
#pragma unroll
        for (int j = 0; j < 4; ++j)
          acc[i][j] = __builtin_amdgcn_mfma_f32_16x16x32_bf16(af[i], bf[j], acc[i][j], 0, 0, 0);
      __builtin_amdgcn_s_setprio(0);
    }
    // ---- phase B (sub-plane 1) ----
    if (t + 1 < nt) STAGE_HALF(nb, (t + 1) * 64, 1);
    {
      short8 af[8], bf[4];
#pragma unroll
      for (int i = 0; i < 8; ++i)
        af[i] = *(const short8*)&lsA[cur][1][(wm + i * 16 + lr) * 32 + (lg ^ rx) * 8];
#pragma unroll
      for (int j = 0; j < 4; ++j)
        bf[j] = *(const short8*)&lsB[cur][1][(wn + j * 16 + lr) * 32 + (lg ^ rx) * 8];
      __builtin_amdgcn_s_setprio(1);
#pragma unroll
      for (int i = 0; i < 8; ++i)
#pragma unroll
        for (int j = 0; j < 4; ++j)
          acc[i][j] = __builtin_amdgcn_mfma_f32_16x16x32_bf16(af[i], bf[j], acc[i][j], 0, 0, 0);
      __builtin_amdgcn_s_setprio(0);
    }
    asm volatile("s_barrier" ::: "memory");  // reads of cur done before reuse
  }
#undef STAGE_HALF
  const size_t cbase = (size_t)(bm * 256 + wm + lg * 4) * N + bn * 256 + wn + lr;
  if (BF16OUT) {
    ushort* Cb = (ushort*)Cv + cbase;
#pragma unroll
    for (int i = 0; i < 8; ++i)
#pragma unroll
      for (int j = 0; j < 4; ++j)
#pragma unroll
        for (int r = 0; r < 4; ++r)
          Cb[(size_t)(i * 16 + r) * N + j * 16] = f2bf(acc[i][j][r]);
  } else {
    float* Cb = (float*)Cv + cbase;
#pragma unroll
    for (int i = 0; i < 8; ++i)
#pragma unroll
      for (int j = 0; j < 4; ++j)
#pragma unroll
        for (int r = 0; r < 4; ++r)
          Cb[(size_t)(i * 16 + r) * N + j * 16] = acc[i][j][r];
  }
}

// ------------- GEMM 128x128 BK=32 (proven round-13 kernel; fc2 only) -------
template <int BF16OUT>
__global__ __launch_bounds__(256) void k_gemm_s(const ushort* __restrict__ A,
                                                const ushort* __restrict__ Bt,
                                                void* __restrict__ Cv,
                                                int K, int N) {
  __shared__ __align__(16) ushort lsA[2][4096];
  __shared__ __align__(16) ushort lsB[2][4096];
  const int tid = threadIdx.x;
  const int bm = blockIdx.x, bn = blockIdx.y;
  const int w = tid >> 6, l = tid & 63;
  const int wm = (w >> 1) * 64, wn = (w & 1) * 64;
  const int lr = l & 15, lg = l >> 4;
  f32x4 acc[4][4] = {};
  const int srow = tid >> 2;
  const int scol = (((tid & 3) ^ ((srow >> 1) & 3))) * 8;
  const ushort* Ag = A + (size_t)(bm * 128 + srow) * K + scol;
  const ushort* Bg = Bt + (size_t)(bn * 128 + srow) * K + scol;
  const int nt = K >> 5;
  const int rxor = (lr >> 1) & 3;

#define GEMM_ISSUE(BUF, KT)                                          \
  {                                                                  \
    GLDS(Ag + (KT), &lsA[BUF][w * 512], 16);                         \
    GLDS(Ag + (size_t)64 * K + (KT), &lsA[BUF][2048 + w * 512], 16); \
    GLDS(Bg + (KT), &lsB[BUF][w * 512], 16);                         \
    GLDS(Bg + (size_t)64 * K + (KT), &lsB[BUF][2048 + w * 512], 16); \
  }

  GEMM_ISSUE(0, 0);
  for (int t = 0; t < nt; ++t) {
    const int cur = t & 1;
    if (t + 1 < nt) {
      GEMM_ISSUE(cur ^ 1, (t + 1) * 32);
      asm volatile("s_waitcnt vmcnt(4)" ::: "memory");
    } else {
      asm volatile("s_waitcnt vmcnt(0)" ::: "memory");
    }
    asm volatile("s_barrier" ::: "memory");
    short8 af[4], bfr[4];
#pragma unroll
    for (int i = 0; i < 4; ++i)
      af[i] = *(const short8*)&lsA[cur][(wm + i * 16 + lr) * 32 + ((lg ^ rxor) * 8)];
#pragma unroll
    for (int j = 0; j < 4; ++j)
      bfr[j] = *(const short8*)&lsB[cur][(wn + j * 16 + lr) * 32 + ((lg ^ rxor) * 8)];
#pragma unroll
    for (int i = 0; i < 4; ++i)
#pragma unroll
      for (int j = 0; j < 4; ++j)
        acc[i][j] = __builtin_amdgcn_mfma_f32_16x16x32_bf16(af[i], bfr[j], acc[i][j], 0, 0, 0);
    asm volatile("s_barrier" ::: "memory");
  }
#undef GEMM_ISSUE
  const size_t cbase = (size_t)(bm * 128 + wm + lg * 4) * N + bn * 128 + wn + lr;
  if (BF16OUT) {
    ushort* Cb = (ushort*)Cv + cbase;
#pragma unroll
    for (int i = 0; i < 4; ++i)
#pragma unroll
      for (int j = 0; j < 4; ++j)
#pragma unroll
        for (int r = 0; r < 4; ++r)
          Cb[(size_t)(i * 16 + r) * N + j * 16] = f2bf(acc[i][j][r]);
  } else {
    float* Cb = (float*)Cv + cbase;
#pragma unroll
    for (int i = 0; i < 4; ++i)
#pragma unroll
      for (int j = 0; j < 4; ++j)
#pragma unroll
        for (int r = 0; r < 4; ++r)
          Cb[(size_t)(i * 16 + r) * N + j * 16] = acc[i][j][r];
  }
}

// ------------- SRU recurrence (round-13 passing version) -------------
__global__ __launch_bounds__(64, 1) void sru_rec8(const ushort* __restrict__ U, int NU,
                                                  const ushort* __restrict__ R, int RS,
                                                  const float* __restrict__ v,
                                                  const float* __restrict__ bb,
                                                  ushort* __restrict__ H) {
  const int lane = threadIdx.x;
  const int blk = blockIdx.x;
  const int b = blk >> 4, rem = blk & 15, dir = rem >> 3, cg = rem & 7;
  const int ch = dir * 512 + cg * 64 + lane;
  const float vf = v[ch], vr = v[1024 + ch];
  const float bfv = bb[ch], brv = bb[1024 + ch];
  const float vfn = -vf, vrn = -vr;
  const float kf0 = -bfv, kr0 = -brv;
  const int tstep = dir ? -1 : 1;
  const int t0 = dir ? 511 : 0;
  const ushort* U01 = U + (size_t)b * 512 * NU + ch * 2;
  const ushort* U2  = U + (size_t)b * 512 * NU + 2048 + ch;
  const ushort* Rb  = R + (size_t)b * 512 * RS + ch;
  ushort* Hb = H + (size_t)b * 512 * 1024 + ch;

  unsigned q01[4][8];
  ushort q2[4][8], qr[4][8];

#define SR_ISSUE(J, TI)                                                        \
  {                                                                            \
    const int base_ = (TI) * 8;                                                \
    _Pragma("unroll")                                                          \
    for (int t = 0; t < 8; ++t) {                                              \
      int tt = t0 + tstep * (base_ + t);                                       \
      q01[J][t] = *(const unsigned*)(U01 + (size_t)tt * NU);                   \
      q2[J][t] = U2[(size_t)tt * NU];                                          \
      qr[J][t] = Rb[(size_t)tt * RS];                                          \
    }                                                                          \
  }

#define SR_COMP(J, TI)                                                         \
  {                                                                            \
    _Pragma("unroll")                                                          \
    for (int s = 0; s < 8; ++s) {                                              \
      float u0 = __builtin_bit_cast(float, q01[J][s] << 16);                   \
      float u1 = __builtin_bit_cast(float, q01[J][s] & 0xffff0000u);           \
      float u2 = bf2f(q2[J][s]);                                               \
      float uR = bf2f(qr[J][s]);                                               \
      float ef = __expf(__builtin_fmaf(vfn, c, kf0 - u1));                     \
      float f = __builtin_amdgcn_rcpf(1.f + ef);                               \
      c = __builtin_fmaf(f, c - u0, u0);                                       \
      float er = __expf(__builtin_fmaf(vrn, c, kr0 - u2));                     \
      float r = __builtin_amdgcn_rcpf(1.f + er);                               \
      float hh = __builtin_fmaf(r, c - uR, uR);                                \
      Hb[(size_t)(t0 + tstep * ((TI) * 8 + s)) * 1024] = f2bf(hh);             \
    }                                                                          \
  }

  SR_ISSUE(0, 0)
  SR_ISSUE(1, 1)
  SR_ISSUE(2, 2)
  float c = 0.f;
#pragma unroll 1
  for (int ii = 0; ii < 15; ++ii) {
#define TILE_J(J)                                                              \
    {                                                                          \
      const int i = ii * 4 + (J);                                              \
      SR_ISSUE((((J) + 3) & 3), i + 3)                                         \
      asm volatile("s_waitcnt vmcnt(63)" ::: "memory");                        \
      SR_COMP(J, i)                                                            \
    }
    TILE_J(0) TILE_J(1) TILE_J(2) TILE_J(3)
#undef TILE_J
  }
  SR_ISSUE(3, 63)
  asm volatile("s_waitcnt vmcnt(63)" ::: "memory");
  SR_COMP(0, 60)
  asm volatile("s_waitcnt vmcnt(48)" ::: "memory");
  SR_COMP(1, 61)
  asm volatile("s_waitcnt vmcnt(24)" ::: "memory");
  SR_COMP(2, 62)
  asm volatile("s_waitcnt vmcnt(0)" ::: "memory");
  SR_COMP(3, 63)
#undef SR_ISSUE
#undef SR_COMP
}

// ------------- head helpers -------------
__global__ __launch_bounds__(256) void k_buildW2(const float* __restrict__ w2l,
                                                 const float* __restrict__ w2m,
                                                 const float* __restrict__ w2k,
                                                 ushort* __restrict__ Wt2) {
  int i = blockIdx.x * 256 + threadIdx.x;
  if (i >= 128 * 1024) return;
  int n = i >> 10, k = i & 1023;
  float vv = 0.f;
  if (n < 21 && k < 512) vv = w2l[k * 21 + n];
  else if (n >= 21 && n < 23 && k >= 512) vv = w2m[(k - 512) * 2 + (n - 21)];
  else if (n >= 23 && n < 25 && k >= 512) vv = w2k[(k - 512) * 2 + (n - 23)];
  Wt2[i] = f2bf(vv);
}

__global__ __launch_bounds__(64) void k_bias25(const float* __restrict__ b1l,
                                               const float* __restrict__ b1a,
                                               const float* __restrict__ w2l,
                                               const float* __restrict__ b2l,
                                               const float* __restrict__ w2m,
                                               const float* __restrict__ b2m,
                                               const float* __restrict__ w2k,
                                               const float* __restrict__ b2k,
                                               float* __restrict__ b2adj) {
  int o = threadIdx.x;
  if (o >= 25) return;
  float s;
  if (o < 21) {
    s = b2l[o];
    for (int k = 0; k < 512; ++k) s += b1l[k] * w2l[k * 21 + o];
  } else if (o < 23) {
    s = b2m[o - 21];
    for (int k = 0; k < 512; ++k) s += b1a[k] * w2m[k * 2 + (o - 21)];
  } else {
    s = b2k[o - 23];
    for (int k = 0; k < 512; ++k) s += b1a[k] * w2k[k * 2 + (o - 23)];
  }
  b2adj[o] = s;
}

__global__ __launch_bounds__(64) void k_act(const float* __restrict__ T,
                                            const float* __restrict__ b2adj,
                                            float* __restrict__ out) {
  const int row = blockIdx.x;
  const int lane = threadIdx.x;
  float myv = 0.f;
  if (lane < 25) myv = T[(size_t)row * 128 + lane] + b2adj[lane];
  float x = (lane < 21) ? myv : -1e30f;
#pragma unroll
  for (int off = 32; off; off >>= 1) x = fmaxf(x, __shfl_xor(x, off));
  float e = (lane < 21) ? expf(myv - x) : 0.f;
#pragma unroll
  for (int off = 32; off; off >>= 1) e += __shfl_xor(e, off);
  float lse = x + logf(e);
  if (lane < 21) {
    out[(size_t)row * 21 + lane] = myv - lse;
  } else if (lane < 23) {
    out[172032 + row * 2 + (lane - 21)] = tanhf(myv) * 3.14159265358979323846f;
  } else if (lane < 25) {
    float sp = (myv > 20.f) ? myv : log1pf(expf(myv));
    out[188416 + row * 2 + (lane - 23)] = 5.f + sp;
  }
}

extern "C" void kernel_launch(void* const* d_in, const int* in_sizes, int n_in,
                              void* d_out, int out_size, void* d_ws, size_t ws_size,
                              hipStream_t stream) {
  (void)in_sizes; (void)n_in; (void)out_size; (void)ws_size;
  const float* input = (const float*)d_in[0];
  const float* sw[6]; const float* sv[6]; const float* sb[6];
  for (int l = 0; l < 6; ++l) {
    sw[l] = (const float*)d_in[2 + 3 * l];
    sv[l] = (const float*)d_in[3 + 3 * l];
    sb[l] = (const float*)d_in[4 + 3 * l];
  }
  const float* fc1lw = (const float*)d_in[20];
  const float* fc1lb = (const float*)d_in[21];
  const float* fc2lw = (const float*)d_in[22];
  const float* fc2lb = (const float*)d_in[23];
  const float* fc1aw = (const float*)d_in[24];
  const float* fc1ab = (const float*)d_in[25];
  const float* fc2mw = (const float*)d_in[26];
  const float* fc2mb = (const float*)d_in[27];
  const float* fc2kw = (const float*)d_in[28];
  const float* fc2kb = (const float*)d_in[29];

  char* ws = (char*)d_ws;
  ushort* U = (ushort*)ws;                                 // 64 MiB (bf16 planar)
  ushort* Hcat2 = (ushort*)ws;                             // 16 MiB (reuses U)
  float* T = (float*)(ws + 67108864);                      // 4 MiB
  ushort* H0 = (ushort*)(ws + 134217728);                  // 16 MiB
  ushort* H1 = (ushort*)(ws + 150994944);                  // 16 MiB
  ushort* X0 = (ushort*)(ws + 167772160);                  // 8 MiB
  const size_t wbase = 176160768;
  ushort* Wtl[6];
  Wtl[0] = (ushort*)(ws + wbase);                          // 4 MiB
  for (int l = 1; l < 6; ++l)
    Wtl[l] = (ushort*)(ws + wbase + 4194304 + (size_t)(l - 1) * 6291456);
  ushort* Wfc = (ushort*)(ws + wbase + 4194304 + 5ull * 6291456);
  ushort* Wt2 = (ushort*)(ws + wbase + 37748736);
  float* b2adj = (float*)(ws + wbase + 38010880);

  // 1. input -> bf16; head weight prep
  k_cvt<<<4096, 256, 0, stream>>>(input, X0, 8192 * 512 / 4);
  k_buildW2<<<512, 256, 0, stream>>>(fc2lw, fc2mw, fc2kw, Wt2);
  k_bias25<<<1, 64, 0, stream>>>(fc1lb, fc1ab, fc2lw, fc2lb, fc2mw, fc2mb,
                                 fc2kw, fc2kb, b2adj);

  // 2. weight transposes
  k_transpose_sru<4><<<dim3(128, 16), dim3(32, 8), 0, stream>>>(sw[0], Wtl[0], 4096, 512);
  for (int l = 1; l < 6; ++l)
    k_transpose_sru<3><<<dim3(96, 32), dim3(32, 8), 0, stream>>>(sw[l], Wtl[l], 3072, 1024);
  k_transpose<<<dim3(16, 32), dim3(32, 8), 0, stream>>>(fc1lw, Wfc, 512, 1024);
  k_transpose<<<dim3(16, 32), dim3(32, 8), 0, stream>>>(fc1aw, Wfc + (size_t)512 * 1024, 512, 1024);

  // 3. SRU layers (256^2 GEMM; U bf16 planar; res from U plane l=0, else H_in)
  for (int l = 0; l < 6; ++l) {
    const ushort* Ain = (l == 0) ? X0 : ((l & 1) ? H0 : H1);
    ushort* Hout = (l & 1) ? H1 : H0;
    int K = (l == 0) ? 512 : 1024;
    int N = (l == 0) ? 4096 : 3072;
    k_gemm256<1><<<dim3(32, N / 256), 512, 0, stream>>>(Ain, Wtl[l], U, K, N);
    if (l == 0)
      sru_rec8<<<256, 64, 0, stream>>>(U, 4096, U + 3072, 4096, sv[l], sb[l], Hout);
    else
      sru_rec8<<<256, 64, 0, stream>>>(U, 3072, Ain, 1024, sv[l], sb[l], Hout);
  }

  // 4. head fc1 (logits|angles fused), bf16 out
  k_gemm256<1><<<dim3(32, 4), 512, 0, stream>>>(H1, Wfc, Hcat2, 1024, 1024);

  // 5. head fc2 (N=128): proven 128^2 kernel, fp32 out
  k_gemm_s<0><<<dim3(64, 1), 256, 0, stream>>>(Hcat2, Wt2, T, 1024, 128);

  // 6. activations -> out
  k_act<<<8192, 64, 0, stream>>>(T, b2adj, (float*)d_out);
}

// Round 17
// 778.527 us; speedup vs baseline: 1.0937x; 1.0937x over previous
//
#include <hip/hip_runtime.h>

typedef __attribute__((ext_vector_type(8))) short short8;
typedef __attribute__((ext_vector_type(4))) float f32x4;

__device__ __forceinline__ ushort f2bf(float x) {
  unsigned u = __builtin_bit_cast(unsigned, x);
  u = (u + 0x7fffu + ((u >> 16) & 1u)) >> 16;
  return (ushort)u;
}
__device__ __forceinline__ float bf2f(ushort x) {
  return __builtin_bit_cast(float, ((unsigned)x) << 16);
}

// global -> LDS direct DMA (k_gemm staging)
#define AS1CP(p) ((const __attribute__((address_space(1))) unsigned int*)(p))
#define AS3CP(p) ((__attribute__((address_space(3))) unsigned int*)(p))
#define GLDS(g, l, SZ) __builtin_amdgcn_global_load_lds(AS1CP(g), AS3CP(l), SZ, 0, 0)

// ---------------- input fp32 -> bf16 ----------------
__global__ __launch_bounds__(256) void k_cvt(const float* __restrict__ in,
                                             ushort* __restrict__ out, int n4) {
  int i = blockIdx.x * 256 + threadIdx.x;
  if (i >= n4) return;
  float4 v = reinterpret_cast<const float4*>(in)[i];
  ushort4 o;
  o.x = f2bf(v.x); o.y = f2bf(v.y); o.z = f2bf(v.z); o.w = f2bf(v.w);
  reinterpret_cast<ushort4*>(out)[i] = o;
}

// ------------- transpose fp32 [K][N] -> bf16 [N][K] (plain) -------------
__global__ __launch_bounds__(256) void k_transpose(const float* __restrict__ W,
                                                   ushort* __restrict__ Wt,
                                                   int N, int K) {
  __shared__ float tile[32][33];
  int bx = blockIdx.x * 32;
  int by = blockIdx.y * 32;
  int tx = threadIdx.x, ty = threadIdx.y;  // 32 x 8
#pragma unroll
  for (int i = 0; i < 32; i += 8)
    tile[ty + i][tx] = W[(size_t)(by + ty + i) * N + bx + tx];
  __syncthreads();
#pragma unroll
  for (int i = 0; i < 32; i += 8)
    Wt[(size_t)(bx + ty + i) * K + by + tx] = f2bf(tile[tx][ty + i]);
}

// ------ transpose + planar-pair permutation for SRU weights ------
// orig col c = ch*KKp + j (ch=0..1023). newcol: j<2 -> ch*2+j ; j==2 -> 2048+ch ;
// j==3 -> 3072+ch. U rows then read as [u0u1 pairs | u2 plane | res plane].
template <int KKp>
__global__ __launch_bounds__(256) void k_transpose_sru(const float* __restrict__ W,
                                                       ushort* __restrict__ Wt,
                                                       int N, int K) {
  __shared__ float tile[32][33];
  int bx = blockIdx.x * 32;
  int by = blockIdx.y * 32;
  int tx = threadIdx.x, ty = threadIdx.y;
#pragma unroll
  for (int i = 0; i < 32; i += 8)
    tile[ty + i][tx] = W[(size_t)(by + ty + i) * N + bx + tx];
  __syncthreads();
#pragma unroll
  for (int i = 0; i < 32; i += 8) {
    int c = bx + ty + i;
    int ch = c / KKp, j = c - ch * KKp;
    int nc = (j < 2) ? (ch * 2 + j) : ((j == 2) ? (2048 + ch) : (3072 + ch));
    Wt[(size_t)nc * K + by + tx] = f2bf(tile[tx][ty + i]);
  }
}

// ------------- GEMM: C[M][N] = A[M][K] bf16 * Bt[N][K] bf16 -------------
// 128x128 tile, BK=64 (two BK=32 sub-tiles), 4 waves. 2-slot LDS ring with
// global_load_lds staging (8 issues/K-step), counted vmcnt(8), raw barrier
// pair per K-step (32 MFMA per pair); both-sides LDS swizzle (conflict-free
// ds_read_b128). K must be a multiple of 64. [round-15 passing version]
template <int BF16OUT>
__global__ __launch_bounds__(256) void k_gemm(const ushort* __restrict__ A,
                                              const ushort* __restrict__ Bt,
                                              void* __restrict__ Cv,
                                              int K, int N) {
  __shared__ __align__(16) ushort lsA[2][2][4096];
  __shared__ __align__(16) ushort lsB[2][2][4096];
  const int tid = threadIdx.x;
  const int bm = blockIdx.x, bn = blockIdx.y;
  const int w = tid >> 6, l = tid & 63;
  const int wm = (w >> 1) * 64, wn = (w & 1) * 64;
  const int lr = l & 15, lg = l >> 4;
  f32x4 acc[4][4] = {};
  const int srow = tid >> 2;                               // 0..63
  const int scol = (((tid & 3) ^ ((srow >> 1) & 3))) * 8;  // swizzled source chunk
  const ushort* Ag = A + (size_t)(bm * 128 + srow) * K + scol;
  const ushort* Bg = Bt + (size_t)(bn * 128 + srow) * K + scol;
  const int nt = K >> 6;
  const int rxor = (lr >> 1) & 3;                          // read-side XOR

#define GEMM_ISSUE(SL, KT)                                                  \
  {                                                                         \
    GLDS(Ag + (KT), &lsA[SL][0][w * 512], 16);                              \
    GLDS(Ag + (size_t)64 * K + (KT), &lsA[SL][0][2048 + w * 512], 16);      \
    GLDS(Bg + (KT), &lsB[SL][0][w * 512], 16);                              \
    GLDS(Bg + (size_t)64 * K + (KT), &lsB[SL][0][2048 + w * 512], 16);      \
    GLDS(Ag + (KT) + 32, &lsA[SL][1][w * 512], 16);                         \
    GLDS(Ag + (size_t)64 * K + (KT) + 32, &lsA[SL][1][2048 + w * 512], 16); \
    GLDS(Bg + (KT) + 32, &lsB[SL][1][w * 512], 16);                         \
    GLDS(Bg + (size_t)64 * K + (KT) + 32, &lsB[SL][1][2048 + w * 512], 16); \
  }

  GEMM_ISSUE(0, 0);
  for (int t = 0; t < nt; ++t) {
    const int cur = t & 1;
    if (t + 1 < nt) {
      GEMM_ISSUE(cur ^ 1, (t + 1) * 64);
      asm volatile("s_waitcnt vmcnt(8)" ::: "memory");  // own slot landed
    } else {
      asm volatile("s_waitcnt vmcnt(0)" ::: "memory");
    }
    asm volatile("s_barrier" ::: "memory");  // all waves' tile-t DMA landed
#pragma unroll
    for (int kk = 0; kk < 2; ++kk) {
      short8 af[4], bfr[4];
#pragma unroll
      for (int i = 0; i < 4; ++i)
        af[i] = *(const short8*)&lsA[cur][kk][(wm + i * 16 + lr) * 32 + ((lg ^ rxor) * 8)];
#pragma unroll
      for (int j = 0; j < 4; ++j)
        bfr[j] = *(const short8*)&lsB[cur][kk][(wn + j * 16 + lr) * 32 + ((lg ^ rxor) * 8)];
#pragma unroll
      for (int i = 0; i < 4; ++i)
#pragma unroll
        for (int j = 0; j < 4; ++j)
          acc[i][j] = __builtin_amdgcn_mfma_f32_16x16x32_bf16(af[i], bfr[j], acc[i][j], 0, 0, 0);
    }
    asm volatile("s_barrier" ::: "memory");  // reads done before slot reuse
  }
#undef GEMM_ISSUE
  const size_t cbase = (size_t)(bm * 128 + wm + lg * 4) * N + bn * 128 + wn + lr;
  if (BF16OUT) {
    ushort* Cb = (ushort*)Cv + cbase;
#pragma unroll
    for (int i = 0; i < 4; ++i)
#pragma unroll
      for (int j = 0; j < 4; ++j)
#pragma unroll
        for (int r = 0; r < 4; ++r)
          Cb[(size_t)(i * 16 + r) * N + j * 16] = f2bf(acc[i][j][r]);
  } else {
    float* Cb = (float*)Cv + cbase;
#pragma unroll
    for (int i = 0; i < 4; ++i)
#pragma unroll
      for (int j = 0; j < 4; ++j)
#pragma unroll
        for (int r = 0; r < 4; ++r)
          Cb[(size_t)(i * 16 + r) * N + j * 16] = acc[i][j][r];
  }
}

// ------------- SRU recurrence v11: planar bf16 U, 32-lane, 2 waves/CU ------
// 512 blocks x 1 wave, lanes 0..31 active; lane owns channel
// ch = dir*512 + cg*32 + lane (cg 0..15). 16384 channels / 32 = 512 waves
// -> 2 waves/CU (vs rec8's 1): doubles outstanding-load capacity per CU.
// u01 dword loads stay full 128B lines; u2/res ushort loads are 64B halves
// (adjacent-cg blocks cover the other half -> L2 absorbs).
// Ring 4 slots x 8 steps, statically indexed; instruction counts per tile
// are IDENTICAL to rec8 (24 loads + 8 stores), so the verified vmcnt
// discipline carries over unchanged: steady vmcnt(63) (72 newer loads),
// tail 63/48/24/0.
__global__ __launch_bounds__(64, 1) void sru_rec8(const ushort* __restrict__ U, int NU,
                                                  const ushort* __restrict__ R, int RS,
                                                  const float* __restrict__ v,
                                                  const float* __restrict__ bb,
                                                  ushort* __restrict__ H) {
  const int lane = threadIdx.x;
  if (lane >= 32) return;  // 32 active lanes
  const int blk = blockIdx.x;                 // 0..511 : b(4) dir(1) cg(4)
  const int b = blk >> 5, rem = blk & 31, dir = rem >> 4, cg = rem & 15;
  const int ch = dir * 512 + cg * 32 + lane;
  const float vf = v[ch], vr = v[1024 + ch];
  const float bfv = bb[ch], brv = bb[1024 + ch];
  const float vfn = -vf, vrn = -vr;
  const float kf0 = -bfv, kr0 = -brv;
  const int tstep = dir ? -1 : 1;
  const int t0 = dir ? 511 : 0;
  const ushort* U01 = U + (size_t)b * 512 * NU + ch * 2;
  const ushort* U2  = U + (size_t)b * 512 * NU + 2048 + ch;
  const ushort* Rb  = R + (size_t)b * 512 * RS + ch;
  ushort* Hb = H + (size_t)b * 512 * 1024 + ch;

  unsigned q01[4][8];
  ushort q2[4][8], qr[4][8];

#define SR_ISSUE(J, TI)                                                        \
  {                                                                            \
    const int base_ = (TI) * 8;                                                \
    _Pragma("unroll")                                                          \
    for (int t = 0; t < 8; ++t) {                                              \
      int tt = t0 + tstep * (base_ + t);                                       \
      q01[J][t] = *(const unsigned*)(U01 + (size_t)tt * NU);                   \
      q2[J][t] = U2[(size_t)tt * NU];                                          \
      qr[J][t] = Rb[(size_t)tt * RS];                                          \
    }                                                                          \
  }

#define SR_COMP(J, TI)                                                         \
  {                                                                            \
    _Pragma("unroll")                                                          \
    for (int s = 0; s < 8; ++s) {                                              \
      float u0 = __builtin_bit_cast(float, q01[J][s] << 16);                   \
      float u1 = __builtin_bit_cast(float, q01[J][s] & 0xffff0000u);           \
      float u2 = bf2f(q2[J][s]);                                               \
      float uR = bf2f(qr[J][s]);                                               \
      float ef = __expf(__builtin_fmaf(vfn, c, kf0 - u1));                     \
      float f = __builtin_amdgcn_rcpf(1.f + ef);                               \
      c = __builtin_fmaf(f, c - u0, u0);                                       \
      float er = __expf(__builtin_fmaf(vrn, c, kr0 - u2));                     \
      float r = __builtin_amdgcn_rcpf(1.f + er);                               \
      float hh = __builtin_fmaf(r, c - uR, uR);                                \
      Hb[(size_t)(t0 + tstep * ((TI) * 8 + s)) * 1024] = f2bf(hh);             \
    }                                                                          \
  }

  SR_ISSUE(0, 0)
  SR_ISSUE(1, 1)
  SR_ISSUE(2, 2)
  float c = 0.f;
#pragma unroll 1
  for (int ii = 0; ii < 15; ++ii) {   // tiles 0..59 (64 tiles = 512 steps)
#define TILE_J(J)                                                              \
    {                                                                          \
      const int i = ii * 4 + (J);                                              \
      SR_ISSUE((((J) + 3) & 3), i + 3)                                         \
      asm volatile("s_waitcnt vmcnt(63)" ::: "memory");                        \
      SR_COMP(J, i)                                                            \
    }
    TILE_J(0) TILE_J(1) TILE_J(2) TILE_J(3)
#undef TILE_J
  }
  // tail: tiles 60..63 (tile 63 issued here; 60..62 issued in loop)
  SR_ISSUE(3, 63)
  asm volatile("s_waitcnt vmcnt(63)" ::: "memory");
  SR_COMP(0, 60)
  asm volatile("s_waitcnt vmcnt(48)" ::: "memory");
  SR_COMP(1, 61)
  asm volatile("s_waitcnt vmcnt(24)" ::: "memory");
  SR_COMP(2, 62)
  asm volatile("s_waitcnt vmcnt(0)" ::: "memory");
  SR_COMP(3, 63)
#undef SR_ISSUE
#undef SR_COMP
}

// ------------- head helpers -------------
__global__ __launch_bounds__(256) void k_buildW2(const float* __restrict__ w2l,
                                                 const float* __restrict__ w2m,
                                                 const float* __restrict__ w2k,
                                                 ushort* __restrict__ Wt2) {
  int i = blockIdx.x * 256 + threadIdx.x;
  if (i >= 128 * 1024) return;
  int n = i >> 10, k = i & 1023;
  float vv = 0.f;
  if (n < 21 && k < 512) vv = w2l[k * 21 + n];
  else if (n >= 21 && n < 23 && k >= 512) vv = w2m[(k - 512) * 2 + (n - 21)];
  else if (n >= 23 && n < 25 && k >= 512) vv = w2k[(k - 512) * 2 + (n - 23)];
  Wt2[i] = f2bf(vv);
}

__global__ __launch_bounds__(64) void k_bias25(const float* __restrict__ b1l,
                                               const float* __restrict__ b1a,
                                               const float* __restrict__ w2l,
                                               const float* __restrict__ b2l,
                                               const float* __restrict__ w2m,
                                               const float* __restrict__ b2m,
                                               const float* __restrict__ w2k,
                                               const float* __restrict__ b2k,
                                               float* __restrict__ b2adj) {
  int o = threadIdx.x;
  if (o >= 25) return;
  float s;
  if (o < 21) {
    s = b2l[o];
    for (int k = 0; k < 512; ++k) s += b1l[k] * w2l[k * 21 + o];
  } else if (o < 23) {
    s = b2m[o - 21];
    for (int k = 0; k < 512; ++k) s += b1a[k] * w2m[k * 2 + (o - 21)];
  } else {
    s = b2k[o - 23];
    for (int k = 0; k < 512; ++k) s += b1a[k] * w2k[k * 2 + (o - 23)];
  }
  b2adj[o] = s;
}

__global__ __launch_bounds__(64) void k_act(const float* __restrict__ T,
                                            const float* __restrict__ b2adj,
                                            float* __restrict__ out) {
  const int row = blockIdx.x;
  const int lane = threadIdx.x;
  float myv = 0.f;
  if (lane < 25) myv = T[(size_t)row * 128 + lane] + b2adj[lane];
  float x = (lane < 21) ? myv : -1e30f;
#pragma unroll
  for (int off = 32; off; off >>= 1) x = fmaxf(x, __shfl_xor(x, off));
  float e = (lane < 21) ? expf(myv - x) : 0.f;
#pragma unroll
  for (int off = 32; off; off >>= 1) e += __shfl_xor(e, off);
  float lse = x + logf(e);
  if (lane < 21) {
    out[(size_t)row * 21 + lane] = myv - lse;
  } else if (lane < 23) {
    out[172032 + row * 2 + (lane - 21)] = tanhf(myv) * 3.14159265358979323846f;
  } else if (lane < 25) {
    float sp = (myv > 20.f) ? myv : log1pf(expf(myv));
    out[188416 + row * 2 + (lane - 23)] = 5.f + sp;
  }
}

extern "C" void kernel_launch(void* const* d_in, const int* in_sizes, int n_in,
                              void* d_out, int out_size, void* d_ws, size_t ws_size,
                              hipStream_t stream) {
  (void)in_sizes; (void)n_in; (void)out_size; (void)ws_size;
  const float* input = (const float*)d_in[0];
  const float* sw[6]; const float* sv[6]; const float* sb[6];
  for (int l = 0; l < 6; ++l) {
    sw[l] = (const float*)d_in[2 + 3 * l];
    sv[l] = (const float*)d_in[3 + 3 * l];
    sb[l] = (const float*)d_in[4 + 3 * l];
  }
  const float* fc1lw = (const float*)d_in[20];
  const float* fc1lb = (const float*)d_in[21];
  const float* fc2lw = (const float*)d_in[22];
  const float* fc2lb = (const float*)d_in[23];
  const float* fc1aw = (const float*)d_in[24];
  const float* fc1ab = (const float*)d_in[25];
  const float* fc2mw = (const float*)d_in[26];
  const float* fc2mb = (const float*)d_in[27];
  const float* fc2kw = (const float*)d_in[28];
  const float* fc2kb = (const float*)d_in[29];

  char* ws = (char*)d_ws;
  ushort* U = (ushort*)ws;                                 // 64 MiB (bf16 planar)
  ushort* Hcat2 = (ushort*)ws;                             // 16 MiB (reuses U)
  float* T = (float*)(ws + 67108864);                      // 4 MiB
  ushort* H0 = (ushort*)(ws + 134217728);                  // 16 MiB
  ushort* H1 = (ushort*)(ws + 150994944);                  // 16 MiB
  ushort* X0 = (ushort*)(ws + 167772160);                  // 8 MiB
  const size_t wbase = 176160768;
  ushort* Wtl[6];
  Wtl[0] = (ushort*)(ws + wbase);                          // 4 MiB
  for (int l = 1; l < 6; ++l)
    Wtl[l] = (ushort*)(ws + wbase + 4194304 + (size_t)(l - 1) * 6291456);
  ushort* Wfc = (ushort*)(ws + wbase + 4194304 + 5ull * 6291456);
  ushort* Wt2 = (ushort*)(ws + wbase + 37748736);
  float* b2adj = (float*)(ws + wbase + 38010880);

  // 1. input -> bf16; head weight prep
  k_cvt<<<4096, 256, 0, stream>>>(input, X0, 8192 * 512 / 4);
  k_buildW2<<<512, 256, 0, stream>>>(fc2lw, fc2mw, fc2kw, Wt2);
  k_bias25<<<1, 64, 0, stream>>>(fc1lb, fc1ab, fc2lw, fc2lb, fc2mw, fc2mb,
                                 fc2kw, fc2kb, b2adj);

  // 2. weight transposes -> bf16 [N][K], SRU ones with planar-pair permutation
  k_transpose_sru<4><<<dim3(128, 16), dim3(32, 8), 0, stream>>>(sw[0], Wtl[0], 4096, 512);
  for (int l = 1; l < 6; ++l)
    k_transpose_sru<3><<<dim3(96, 32), dim3(32, 8), 0, stream>>>(sw[l], Wtl[l], 3072, 1024);
  k_transpose<<<dim3(16, 32), dim3(32, 8), 0, stream>>>(fc1lw, Wfc, 512, 1024);
  k_transpose<<<dim3(16, 32), dim3(32, 8), 0, stream>>>(fc1aw, Wfc + (size_t)512 * 1024, 512, 1024);

  // 3. SRU layers (U is bf16 planar; res from U plane for l=0, else H_in)
  for (int l = 0; l < 6; ++l) {
    const ushort* Ain = (l == 0) ? X0 : ((l & 1) ? H0 : H1);
    ushort* Hout = (l & 1) ? H1 : H0;
    int K = (l == 0) ? 512 : 1024;
    int N = (l == 0) ? 4096 : 3072;
    k_gemm<1><<<dim3(64, N / 128), 256, 0, stream>>>(Ain, Wtl[l], U, K, N);
    if (l == 0)
      sru_rec8<<<512, 64, 0, stream>>>(U, 4096, U + 3072, 4096, sv[l], sb[l], Hout);
    else
      sru_rec8<<<512, 64, 0, stream>>>(U, 3072, Ain, 1024, sv[l], sb[l], Hout);
  }

  // 4. head fc1 (logits|angles fused), bf16 out: [8192,1024] = H1 x Wfc
  k_gemm<1><<<dim3(64, 8), 256, 0, stream>>>(H1, Wfc, Hcat2, 1024, 1024);

  // 5. head fc2: [8192,128] = Hcat2[8192,1024] x Wt2[128,1024] (fp32 out)
  k_gemm<0><<<dim3(64, 1), 256, 0, stream>>>(Hcat2, Wt2, T, 1024, 128);

  // 6. activations -> out
  k_act<<<8192, 64, 0, stream>>>(T, b2adj, (float*)d_out);
}

// Round 18
// 742.997 us; speedup vs baseline: 1.1460x; 1.0478x over previous
//
#include <hip/hip_runtime.h>

typedef __attribute__((ext_vector_type(8))) short short8;
typedef __attribute__((ext_vector_type(4))) float f32x4;

__device__ __forceinline__ ushort f2bf(float x) {
  unsigned u = __builtin_bit_cast(unsigned, x);
  u = (u + 0x7fffu + ((u >> 16) & 1u)) >> 16;
  return (ushort)u;
}
__device__ __forceinline__ float bf2f(ushort x) {
  return __builtin_bit_cast(float, ((unsigned)x) << 16);
}

// global -> LDS direct DMA (k_gemm staging)
#define AS1CP(p) ((const __attribute__((address_space(1))) unsigned int*)(p))
#define AS3CP(p) ((__attribute__((address_space(3))) unsigned int*)(p))
#define GLDS(g, l, SZ) __builtin_amdgcn_global_load_lds(AS1CP(g), AS3CP(l), SZ, 0, 0)

// ---------------- input fp32 -> bf16 ----------------
__global__ __launch_bounds__(256) void k_cvt(const float* __restrict__ in,
                                             ushort* __restrict__ out, int n4) {
  int i = blockIdx.x * 256 + threadIdx.x;
  if (i >= n4) return;
  float4 v = reinterpret_cast<const float4*>(in)[i];
  ushort4 o;
  o.x = f2bf(v.x); o.y = f2bf(v.y); o.z = f2bf(v.z); o.w = f2bf(v.w);
  reinterpret_cast<ushort4*>(out)[i] = o;
}

// ------------- transpose fp32 [K][N] -> bf16 [N][K] (plain) -------------
__global__ __launch_bounds__(256) void k_transpose(const float* __restrict__ W,
                                                   ushort* __restrict__ Wt,
                                                   int N, int K) {
  __shared__ float tile[32][33];
  int bx = blockIdx.x * 32;
  int by = blockIdx.y * 32;
  int tx = threadIdx.x, ty = threadIdx.y;  // 32 x 8
#pragma unroll
  for (int i = 0; i < 32; i += 8)
    tile[ty + i][tx] = W[(size_t)(by + ty + i) * N + bx + tx];
  __syncthreads();
#pragma unroll
  for (int i = 0; i < 32; i += 8)
    Wt[(size_t)(bx + ty + i) * K + by + tx] = f2bf(tile[tx][ty + i]);
}

// ------ transpose + PLANE-MAJOR permutation for SRU weights ------
// orig col c = ch*KKp + j (ch = dir*512+h in 0..1023, j = 0..KKp-1).
// new row f = j*1024 + ch  ->  U planes [j][ch][bt] after swapped GEMM.
template <int KKp>
__global__ __launch_bounds__(256) void k_transpose_sru(const float* __restrict__ W,
                                                       ushort* __restrict__ Wt,
                                                       int N, int K) {
  __shared__ float tile[32][33];
  int bx = blockIdx.x * 32;
  int by = blockIdx.y * 32;
  int tx = threadIdx.x, ty = threadIdx.y;
#pragma unroll
  for (int i = 0; i < 32; i += 8)
    tile[ty + i][tx] = W[(size_t)(by + ty + i) * N + bx + tx];
  __syncthreads();
#pragma unroll
  for (int i = 0; i < 32; i += 8) {
    int c = bx + ty + i;
    int ch = c / KKp, j = c - ch * KKp;
    int nc = j * 1024 + ch;
    Wt[(size_t)nc * K + by + tx] = f2bf(tile[tx][ty + i]);
  }
}

// ------------- GEMM: C[M][N] = A[M][K] bf16 * Bt[N][K] bf16 -------------
// 128x128 tile, BK=64 (two BK=32 sub-tiles), 4 waves. 2-slot LDS ring with
// global_load_lds staging (8 issues/K-step), counted vmcnt(8), raw barrier
// pair per K-step (32 MFMA per pair); both-sides LDS swizzle (conflict-free
// ds_read_b128). K multiple of 64. [round-15 verified kernel, untouched]
template <int BF16OUT>
__global__ __launch_bounds__(256) void k_gemm(const ushort* __restrict__ A,
                                              const ushort* __restrict__ Bt,
                                              void* __restrict__ Cv,
                                              int K, int N) {
  __shared__ __align__(16) ushort lsA[2][2][4096];
  __shared__ __align__(16) ushort lsB[2][2][4096];
  const int tid = threadIdx.x;
  const int bm = blockIdx.x, bn = blockIdx.y;
  const int w = tid >> 6, l = tid & 63;
  const int wm = (w >> 1) * 64, wn = (w & 1) * 64;
  const int lr = l & 15, lg = l >> 4;
  f32x4 acc[4][4] = {};
  const int srow = tid >> 2;                               // 0..63
  const int scol = (((tid & 3) ^ ((srow >> 1) & 3))) * 8;  // swizzled source chunk
  const ushort* Ag = A + (size_t)(bm * 128 + srow) * K + scol;
  const ushort* Bg = Bt + (size_t)(bn * 128 + srow) * K + scol;
  const int nt = K >> 6;
  const int rxor = (lr >> 1) & 3;                          // read-side XOR

#define GEMM_ISSUE(SL, KT)                                                  \
  {                                                                         \
    GLDS(Ag + (KT), &lsA[SL][0][w * 512], 16);                              \
    GLDS(Ag + (size_t)64 * K + (KT), &lsA[SL][0][2048 + w * 512], 16);      \
    GLDS(Bg + (KT), &lsB[SL][0][w * 512], 16);                              \
    GLDS(Bg + (size_t)64 * K + (KT), &lsB[SL][0][2048 + w * 512], 16);      \
    GLDS(Ag + (KT) + 32, &lsA[SL][1][w * 512], 16);                         \
    GLDS(Ag + (size_t)64 * K + (KT) + 32, &lsA[SL][1][2048 + w * 512], 16); \
    GLDS(Bg + (KT) + 32, &lsB[SL][1][w * 512], 16);                         \
    GLDS(Bg + (size_t)64 * K + (KT) + 32, &lsB[SL][1][2048 + w * 512], 16); \
  }

  GEMM_ISSUE(0, 0);
  for (int t = 0; t < nt; ++t) {
    const int cur = t & 1;
    if (t + 1 < nt) {
      GEMM_ISSUE(cur ^ 1, (t + 1) * 64);
      asm volatile("s_waitcnt vmcnt(8)" ::: "memory");
    } else {
      asm volatile("s_waitcnt vmcnt(0)" ::: "memory");
    }
    asm volatile("s_barrier" ::: "memory");
#pragma unroll
    for (int kk = 0; kk < 2; ++kk) {
      short8 af[4], bfr[4];
#pragma unroll
      for (int i = 0; i < 4; ++i)
        af[i] = *(const short8*)&lsA[cur][kk][(wm + i * 16 + lr) * 32 + ((lg ^ rxor) * 8)];
#pragma unroll
      for (int j = 0; j < 4; ++j)
        bfr[j] = *(const short8*)&lsB[cur][kk][(wn + j * 16 + lr) * 32 + ((lg ^ rxor) * 8)];
#pragma unroll
      for (int i = 0; i < 4; ++i)
#pragma unroll
        for (int j = 0; j < 4; ++j)
          acc[i][j] = __builtin_amdgcn_mfma_f32_16x16x32_bf16(af[i], bfr[j], acc[i][j], 0, 0, 0);
    }
    asm volatile("s_barrier" ::: "memory");
  }
#undef GEMM_ISSUE
  const size_t cbase = (size_t)(bm * 128 + wm + lg * 4) * N + bn * 128 + wn + lr;
  if (BF16OUT) {
    ushort* Cb = (ushort*)Cv + cbase;
#pragma unroll
    for (int i = 0; i < 4; ++i)
#pragma unroll
      for (int j = 0; j < 4; ++j)
#pragma unroll
        for (int r = 0; r < 4; ++r)
          Cb[(size_t)(i * 16 + r) * N + j * 16] = f2bf(acc[i][j][r]);
  } else {
    float* Cb = (float*)Cv + cbase;
#pragma unroll
    for (int i = 0; i < 4; ++i)
#pragma unroll
      for (int j = 0; j < 4; ++j)
#pragma unroll
        for (int r = 0; r < 4; ++r)
          Cb[(size_t)(i * 16 + r) * N + j * 16] = acc[i][j][r];
  }
}

// ------------- SRU recurrence v12: [plane][ch][bt] U, 1 dwordx4 / plane ----
// U planes (each [1024 ch][8192 bt]): u0, u1, u2 (+ res plane for layer 0).
// Rp: residual plane, SAME [1024][8192] layout (layer0: U+3*PL; else Hres
// written by previous sru). 256 blocks x 64 lanes; lane owns ch = cg*64+lane,
// block b = blk>>4. Per tile (8 timesteps): FOUR dwordx4 loads (one per
// plane) -> 8-slot register ring (128 VGPR), lookahead 7 (28KB in flight).
// dir = ch>>9: tile covers bt [tb, tb+7] (tb = dir? 504-8i : 8i); element
// e = dir?7-s:s gives timestep t = tb+e. Outputs: H [bt][1024] per-step
// (coalesced 128B/step across wave) + packed 16B Hres [ch][bt] per tile.
// Loads-only vmcnt: steady wait 28 (7 tiles x 4 loads newer); tail
// 24/20/16/12/8/4/0.
template <int WRITE_NEXT>
__global__ __launch_bounds__(64, 1) void sru_rec10(const ushort* __restrict__ U,
                                                   const ushort* __restrict__ Rp,
                                                   const float* __restrict__ v,
                                                   const float* __restrict__ bb,
                                                   ushort* __restrict__ H,
                                                   ushort* __restrict__ Hres) {
  const size_t PL = (size_t)1024 * 8192;
  const int lane = threadIdx.x;
  const int blk = blockIdx.x;                 // 0..255 : b(4) cg(4)
  const int b = blk >> 4, cg = blk & 15;
  const int ch = cg * 64 + lane;              // 0..1023
  const int dir = ch >> 9;
  const float vf = v[ch], vr = v[1024 + ch];
  const float bfv = bb[ch], brv = bb[1024 + ch];
  const float vfn = -vf, vrn = -vr;
  const float kf0 = -bfv, kr0 = -brv;
  const size_t rowoff = (size_t)ch * 8192 + b * 512;
  const ushort* U0 = U + rowoff;
  const ushort* U1 = U0 + PL;
  const ushort* U2 = U0 + 2 * PL;
  const ushort* Rb = Rp + rowoff;
  ushort* Hb = H + (size_t)b * 512 * 1024 + ch;
  ushort* Hr = Hres + rowoff;

  short8 q0[8], q1[8], q2[8], qr[8];

#define SR_ISSUE(J, TI)                                                        \
  {                                                                            \
    const int tb_ = dir ? (504 - (TI) * 8) : ((TI) * 8);                       \
    q0[J] = *(const short8*)(U0 + tb_);                                        \
    q1[J] = *(const short8*)(U1 + tb_);                                        \
    q2[J] = *(const short8*)(U2 + tb_);                                        \
    qr[J] = *(const short8*)(Rb + tb_);                                        \
  }

#define SR_COMP(J, TI)                                                         \
  {                                                                            \
    const int tb_ = dir ? (504 - (TI) * 8) : ((TI) * 8);                       \
    short8 hv = {};                                                            \
    _Pragma("unroll")                                                          \
    for (int s = 0; s < 8; ++s) {                                              \
      const int e0 = s, e1 = 7 - s;                                            \
      const int e = dir ? e1 : e0;                                             \
      float u0 = bf2f((ushort)(dir ? q0[J][e1] : q0[J][e0]));                  \
      float u1 = bf2f((ushort)(dir ? q1[J][e1] : q1[J][e0]));                  \
      float u2 = bf2f((ushort)(dir ? q2[J][e1] : q2[J][e0]));                  \
      float uR = bf2f((ushort)(dir ? qr[J][e1] : qr[J][e0]));                  \
      float ef = __expf(__builtin_fmaf(vfn, c, kf0 - u1));                     \
      float f = __builtin_amdgcn_rcpf(1.f + ef);                               \
      c = __builtin_fmaf(f, c - u0, u0);                                       \
      float er = __expf(__builtin_fmaf(vrn, c, kr0 - u2));                     \
      float r = __builtin_amdgcn_rcpf(1.f + er);                               \
      float hh = __builtin_fmaf(r, c - uR, uR);                                \
      ushort hb = f2bf(hh);                                                    \
      Hb[(size_t)(tb_ + e) * 1024] = hb;                                       \
      if (WRITE_NEXT) { if (dir) hv[e1] = (short)hb; else hv[e0] = (short)hb; }\
    }                                                                          \
    if (WRITE_NEXT) *(short8*)(Hr + tb_) = hv;                                 \
  }

  SR_ISSUE(0, 0) SR_ISSUE(1, 1) SR_ISSUE(2, 2) SR_ISSUE(3, 3)
  SR_ISSUE(4, 4) SR_ISSUE(5, 5) SR_ISSUE(6, 6)
  float c = 0.f;
#pragma unroll 1
  for (int ii = 0; ii < 7; ++ii) {   // tiles 0..55
#define TILE_J(J)                                                              \
    {                                                                          \
      const int i = ii * 8 + (J);                                              \
      SR_ISSUE((((J) + 7) & 7), i + 7)                                         \
      asm volatile("s_waitcnt vmcnt(28)" ::: "memory");                        \
      SR_COMP(J, i)                                                            \
    }
    TILE_J(0) TILE_J(1) TILE_J(2) TILE_J(3)
    TILE_J(4) TILE_J(5) TILE_J(6) TILE_J(7)
#undef TILE_J
  }
  // tail: tiles 56..63 (tile 63 issued at i=56)
  SR_ISSUE(7, 63)
  asm volatile("s_waitcnt vmcnt(28)" ::: "memory"); SR_COMP(0, 56)
  asm volatile("s_waitcnt vmcnt(24)" ::: "memory"); SR_COMP(1, 57)
  asm volatile("s_waitcnt vmcnt(20)" ::: "memory"); SR_COMP(2, 58)
  asm volatile("s_waitcnt vmcnt(16)" ::: "memory"); SR_COMP(3, 59)
  asm volatile("s_waitcnt vmcnt(12)" ::: "memory"); SR_COMP(4, 60)
  asm volatile("s_waitcnt vmcnt(8)" ::: "memory");  SR_COMP(5, 61)
  asm volatile("s_waitcnt vmcnt(4)" ::: "memory");  SR_COMP(6, 62)
  asm volatile("s_waitcnt vmcnt(0)" ::: "memory");  SR_COMP(7, 63)
#undef SR_ISSUE
#undef SR_COMP
}

// ------------- head helpers -------------
__global__ __launch_bounds__(256) void k_buildW2(const float* __restrict__ w2l,
                                                 const float* __restrict__ w2m,
                                                 const float* __restrict__ w2k,
                                                 ushort* __restrict__ Wt2) {
  int i = blockIdx.x * 256 + threadIdx.x;
  if (i >= 128 * 1024) return;
  int n = i >> 10, k = i & 1023;
  float vv = 0.f;
  if (n < 21 && k < 512) vv = w2l[k * 21 + n];
  else if (n >= 21 && n < 23 && k >= 512) vv = w2m[(k - 512) * 2 + (n - 21)];
  else if (n >= 23 && n < 25 && k >= 512) vv = w2k[(k - 512) * 2 + (n - 23)];
  Wt2[i] = f2bf(vv);
}

__global__ __launch_bounds__(64) void k_bias25(const float* __restrict__ b1l,
                                               const float* __restrict__ b1a,
                                               const float* __restrict__ w2l,
                                               const float* __restrict__ b2l,
                                               const float* __restrict__ w2m,
                                               const float* __restrict__ b2m,
                                               const float* __restrict__ w2k,
                                               const float* __restrict__ b2k,
                                               float* __restrict__ b2adj) {
  int o = threadIdx.x;
  if (o >= 25) return;
  float s;
  if (o < 21) {
    s = b2l[o];
    for (int k = 0; k < 512; ++k) s += b1l[k] * w2l[k * 21 + o];
  } else if (o < 23) {
    s = b2m[o - 21];
    for (int k = 0; k < 512; ++k) s += b1a[k] * w2m[k * 2 + (o - 21)];
  } else {
    s = b2k[o - 23];
    for (int k = 0; k < 512; ++k) s += b1a[k] * w2k[k * 2 + (o - 23)];
  }
  b2adj[o] = s;
}

__global__ __launch_bounds__(64) void k_act(const float* __restrict__ T,
                                            const float* __restrict__ b2adj,
                                            float* __restrict__ out) {
  const int row = blockIdx.x;
  const int lane = threadIdx.x;
  float myv = 0.f;
  if (lane < 25) myv = T[(size_t)row * 128 + lane] + b2adj[lane];
  float x = (lane < 21) ? myv : -1e30f;
#pragma unroll
  for (int off = 32; off; off >>= 1) x = fmaxf(x, __shfl_xor(x, off));
  float e = (lane < 21) ? expf(myv - x) : 0.f;
#pragma unroll
  for (int off = 32; off; off >>= 1) e += __shfl_xor(e, off);
  float lse = x + logf(e);
  if (lane < 21) {
    out[(size_t)row * 21 + lane] = myv - lse;
  } else if (lane < 23) {
    out[172032 + row * 2 + (lane - 21)] = tanhf(myv) * 3.14159265358979323846f;
  } else if (lane < 25) {
    float sp = (myv > 20.f) ? myv : log1pf(expf(myv));
    out[188416 + row * 2 + (lane - 23)] = 5.f + sp;
  }
}

extern "C" void kernel_launch(void* const* d_in, const int* in_sizes, int n_in,
                              void* d_out, int out_size, void* d_ws, size_t ws_size,
                              hipStream_t stream) {
  (void)in_sizes; (void)n_in; (void)out_size; (void)ws_size;
  const float* input = (const float*)d_in[0];
  const float* sw[6]; const float* sv[6]; const float* sb[6];
  for (int l = 0; l < 6; ++l) {
    sw[l] = (const float*)d_in[2 + 3 * l];
    sv[l] = (const float*)d_in[3 + 3 * l];
    sb[l] = (const float*)d_in[4 + 3 * l];
  }
  const float* fc1lw = (const float*)d_in[20];
  const float* fc1lb = (const float*)d_in[21];
  const float* fc2lw = (const float*)d_in[22];
  const float* fc2lb = (const float*)d_in[23];
  const float* fc1aw = (const float*)d_in[24];
  const float* fc1ab = (const float*)d_in[25];
  const float* fc2mw = (const float*)d_in[26];
  const float* fc2mb = (const float*)d_in[27];
  const float* fc2kw = (const float*)d_in[28];
  const float* fc2kb = (const float*)d_in[29];

  char* ws = (char*)d_ws;
  ushort* U = (ushort*)ws;                                 // 64 MiB [4096][8192] planes
  ushort* Hcat2 = (ushort*)ws;                             // 16 MiB (reuses U after layers)
  float* T = (float*)(ws + 33554432);                      // 4 MiB (inside U, used post-fc1)
  ushort* HresA = (ushort*)(ws + 67108864);                // 16 MiB [1024][8192]
  ushort* HresB = (ushort*)(ws + 83886080);                // 16 MiB
  ushort* H0 = (ushort*)(ws + 134217728);                  // 16 MiB [bt][1024]
  ushort* H1 = (ushort*)(ws + 150994944);                  // 16 MiB
  ushort* X0 = (ushort*)(ws + 167772160);                  // 8 MiB [bt][512]
  const size_t wbase = 176160768;
  ushort* Wtl[6];
  Wtl[0] = (ushort*)(ws + wbase);                          // 4 MiB
  for (int l = 1; l < 6; ++l)
    Wtl[l] = (ushort*)(ws + wbase + 4194304 + (size_t)(l - 1) * 6291456);
  ushort* Wfc = (ushort*)(ws + wbase + 4194304 + 5ull * 6291456);
  ushort* Wt2 = (ushort*)(ws + wbase + 37748736);
  float* b2adj = (float*)(ws + wbase + 38010880);

  // 1. input -> bf16; head weight prep
  k_cvt<<<4096, 256, 0, stream>>>(input, X0, 8192 * 512 / 4);
  k_buildW2<<<512, 256, 0, stream>>>(fc2lw, fc2mw, fc2kw, Wt2);
  k_bias25<<<1, 64, 0, stream>>>(fc1lb, fc1ab, fc2lw, fc2lb, fc2mw, fc2mb,
                                 fc2kw, fc2kb, b2adj);

  // 2. weight transposes: SRU ones plane-major (f = j*1024 + ch); head plain
  k_transpose_sru<4><<<dim3(128, 16), dim3(32, 8), 0, stream>>>(sw[0], Wtl[0], 4096, 512);
  for (int l = 1; l < 6; ++l)
    k_transpose_sru<3><<<dim3(96, 32), dim3(32, 8), 0, stream>>>(sw[l], Wtl[l], 3072, 1024);
  k_transpose<<<dim3(16, 32), dim3(32, 8), 0, stream>>>(fc1lw, Wfc, 512, 1024);
  k_transpose<<<dim3(16, 32), dim3(32, 8), 0, stream>>>(fc1aw, Wfc + (size_t)512 * 1024, 512, 1024);

  // 3. SRU layers: swapped-operand GEMM  U[f][bt] = Wt[f][k] * Ain[bt][k];
  //    sru reads U planes + res plane (l0: U plane 3; else Hres ping-pong).
  const size_t PL = (size_t)1024 * 8192;
  for (int l = 0; l < 6; ++l) {
    const ushort* Ain = (l == 0) ? X0 : ((l & 1) ? H0 : H1);
    ushort* Hout = (l & 1) ? H1 : H0;
    int K = (l == 0) ? 512 : 1024;
    int NF = (l == 0) ? 4096 : 3072;
    k_gemm<1><<<dim3(NF / 128, 64), 256, 0, stream>>>(Wtl[l], Ain, U, K, 8192);
    const ushort* Rp = (l == 0) ? (U + 3 * PL) : ((l & 1) ? HresA : HresB);
    ushort* Hro = (l & 1) ? HresB : HresA;
    if (l < 5)
      sru_rec10<1><<<256, 64, 0, stream>>>(U, Rp, sv[l], sb[l], Hout, Hro);
    else
      sru_rec10<0><<<256, 64, 0, stream>>>(U, Rp, sv[l], sb[l], Hout, Hro);
  }

  // 4. head fc1 (logits|angles fused), bf16 out: [8192,1024] = H1 x Wfc
  k_gemm<1><<<dim3(64, 8), 256, 0, stream>>>(H1, Wfc, Hcat2, 1024, 1024);

  // 5. head fc2: [8192,128] = Hcat2[8192,1024] x Wt2[128,1024] (fp32 out)
  k_gemm<0><<<dim3(64, 1), 256, 0, stream>>>(Hcat2, Wt2, T, 1024, 128);

  // 6. activations -> out
  k_act<<<8192, 64, 0, stream>>>(T, b2adj, (float*)d_out);
}